// Round 9
// baseline (381.573 us; speedup 1.0000x reference)
//
#include <hip/hip_runtime.h>
#include <hip/hip_bf16.h>

using bf16x8 = __attribute__((ext_vector_type(8))) short;
using f32x4  = __attribute__((ext_vector_type(4))) float;

// ---------- dtype-dispatched load helpers ----------
__device__ __forceinline__ float ldf(const void* p, size_t i, float isf){
  if (isf > 0.5f) return ((const float*)p)[i];
  unsigned int u = ((unsigned int)((const unsigned short*)p)[i]) << 16;
  return __uint_as_float(u);
}
__device__ __forceinline__ unsigned short f2bf(float v){
  unsigned int u = __float_as_uint(v);
  u = (u + 0x7FFFu + ((u >> 16) & 1u)) >> 16;   // RNE
  return (unsigned short)u;
}
__device__ __forceinline__ unsigned int pk2(float a, float b){
  return (unsigned int)f2bf(a) | ((unsigned int)f2bf(b) << 16);
}
__device__ __forceinline__ float lo16(unsigned int u){ return __uint_as_float(u << 16); }
__device__ __forceinline__ float hi16(unsigned int u){ return __uint_as_float(u & 0xFFFF0000u); }
__device__ __forceinline__ float bfh(unsigned short h){ return __uint_as_float(((unsigned int)h) << 16); }

// ---------- diagnostics ----------
__global__ void k_fill(unsigned short* o, unsigned short v, int n){
  int i = blockIdx.x*blockDim.x + threadIdx.x;
  if (i < n) o[i] = v;
}

// ---------- dtype detector ----------
__global__ void k_detect(const unsigned short* xh, const unsigned int* eu,
                         float* flag, int nelemX, long long E){
  __shared__ int sf32, si64;
  if (threadIdx.x == 0){ sf32 = 0; si64 = 1; }
  __syncthreads();
  int t = threadIdx.x;
  int i = 2*t;
  if (i < nelemX){
    unsigned e8 = (xh[i] >> 7) & 0xFFu;
    if (e8 >= 140u) sf32 = 1;
  }
  if ((long long)(2*t + 1) < 2*E){
    if (eu[2*t + 1] != 0u) si64 = 0;
  }
  __syncthreads();
  if (t == 0){ flag[0] = (float)sf32; flag[1] = (float)si64; }
}

// ---------- weight pre-convert: transposed bf16 for MFMA B-operand, fp32 for W4 ----------
__global__ void k_cvtW(const void* W1, const void* W2, const void* W3, const void* W4,
                       const float* __restrict__ flag,
                       unsigned short* __restrict__ Wt1, unsigned short* __restrict__ Wt2,
                       unsigned short* __restrict__ Wt3, float* __restrict__ W4f){
  float isf = flag[0];
  int t = blockIdx.x*blockDim.x + threadIdx.x;
  if (t < 3072){ int nn = t >> 5, k = t & 31; Wt1[t] = f2bf(ldf(W1, (size_t)96*k + nn, isf)); }
  if (t < 9216){
    int nn = t/96, k = t - 96*nn;
    Wt2[t] = f2bf(ldf(W2, (size_t)96*k + nn, isf));
    Wt3[t] = f2bf(ldf(W3, (size_t)96*k + nn, isf));
  }
  if (t < 192) W4f[t] = ldf(W4, t, isf);
}

// ---------- CSR build ----------
__global__ void k_cnt(const int* __restrict__ ei, const float* __restrict__ flag,
                      int* __restrict__ cnt, long long E, int n){
  long long i = (long long)blockIdx.x*blockDim.x + threadIdx.x;
  if (i >= E) return;
  int d = (flag[1] > 0.5f) ? ei[2*E + 2*i] : ei[E + i];
  if ((unsigned)d < (unsigned)n) atomicAdd(&cnt[d], 1);
}

__global__ void k_bsum(const int* __restrict__ cnt, int* __restrict__ bsum, int n){
  int i = blockIdx.x*256 + threadIdx.x;
  int v = (i < n) ? cnt[i] : 0;
  #pragma unroll
  for (int off = 32; off; off >>= 1) v += __shfl_down(v, off, 64);
  __shared__ int w[4];
  if ((threadIdx.x & 63) == 0) w[threadIdx.x >> 6] = v;
  __syncthreads();
  if (threadIdx.x == 0) bsum[blockIdx.x] = w[0]+w[1]+w[2]+w[3];
}

__global__ void k_sscan(const int* __restrict__ bsum, int* __restrict__ boff,
                        int* __restrict__ rowstN, int nb){
  int t = threadIdx.x;
  int v = (t < nb) ? bsum[t] : 0;
  int lane = t & 63, wid = t >> 6;
  int s = v;
  #pragma unroll
  for (int off = 1; off < 64; off <<= 1){
    int u = __shfl_up(s, off, 64);
    if (lane >= off) s += u;
  }
  __shared__ int wt[4];
  if (lane == 63) wt[wid] = s;
  __syncthreads();
  int add = 0;
  for (int w = 0; w < wid; ++w) add += wt[w];
  int incl = s + add;
  if (t < nb) boff[t] = incl - v;
  if (t == nb - 1) *rowstN = incl;
}

// also initializes cursor[i] = rowst[i] so fill_slots needs no rowst read
__global__ void k_emit(const int* __restrict__ cnt, const int* __restrict__ boff,
                       int* __restrict__ rowst, int* __restrict__ cursor,
                       float* __restrict__ dinv, int n){
  int i = blockIdx.x*256 + threadIdx.x;
  int v = (i < n) ? cnt[i] : 0;
  int lane = threadIdx.x & 63, wid = threadIdx.x >> 6;
  int s = v;
  #pragma unroll
  for (int off = 1; off < 64; off <<= 1){
    int u = __shfl_up(s, off, 64);
    if (lane >= off) s += u;
  }
  __shared__ int wt[4];
  if (lane == 63) wt[wid] = s;
  __syncthreads();
  int add = 0;
  for (int w = 0; w < wid; ++w) add += wt[w];
  if (i < n){
    int r = boff[blockIdx.x] + add + s - v;
    rowst[i] = r;
    cursor[i] = r;
    dinv[i]  = rsqrtf((float)(1 + v));
  }
}

// cursor pre-initialized to rowst: absolute slot straight from the atomic
__global__ void k_fill_slots(const int* __restrict__ ei, const float* __restrict__ flag,
                             int* __restrict__ cursor, int* __restrict__ csr,
                             long long E, int n){
  long long i = (long long)blockIdx.x*blockDim.x + threadIdx.x;
  if (i >= E) return;
  int s, d;
  if (flag[1] > 0.5f){ s = ei[2*i]; d = ei[2*E + 2*i]; }
  else               { s = ei[i];   d = ei[E + i];     }
  if ((unsigned)s < (unsigned)n && (unsigned)d < (unsigned)n){
    int p = atomicAdd(&cursor[d], 1);
    csr[p] = s;
  }
}

// ---------- MFMA layer 1: HS = dinv * (x @ W1), x N*32 ----------
__global__ __launch_bounds__(256) void k_lin1m(const void* __restrict__ x,
      const unsigned short* __restrict__ Wt1b, const float* __restrict__ flag,
      const float* __restrict__ dinv, unsigned short* __restrict__ HS, int n){
  __shared__ __align__(16) unsigned short Xs[64][40];
  __shared__ __align__(16) unsigned short Wt[96][40];
  int t = threadIdx.x;
  float isf = flag[0];
  for (int q = t; q < 384; q += 256){
    uint4 v = ((const uint4*)Wt1b)[q];
    *(uint4*)&Wt[q >> 2][(q & 3)*8] = v;
  }
  {
    int row = t >> 2, part = t & 3;
    int node = blockIdx.x*64 + row;
    uint4 o;
    if (node < n){
      if (isf > 0.5f){
        const float* xr = (const float*)x + (size_t)32*node + 8*part;
        o.x = pk2(xr[0], xr[1]); o.y = pk2(xr[2], xr[3]);
        o.z = pk2(xr[4], xr[5]); o.w = pk2(xr[6], xr[7]);
      } else {
        o = ((const uint4*)x)[(size_t)4*node + part];
      }
    } else { o.x = o.y = o.z = o.w = 0u; }
    *(uint4*)&Xs[row][8*part] = o;
  }
  __syncthreads();

  int wv = t >> 6, lane = t & 63;
  int m = lane & 15, quad = lane >> 4;
  bf16x8 av = *(const bf16x8*)&Xs[16*wv + m][8*quad];
  f32x4 acc[6];
  #pragma unroll
  for (int c = 0; c < 6; ++c) acc[c] = (f32x4)(0.f);
  #pragma unroll
  for (int c = 0; c < 6; ++c){
    bf16x8 bv = *(const bf16x8*)&Wt[16*c + m][8*quad];
    acc[c] = __builtin_amdgcn_mfma_f32_16x16x32_bf16(av, bv, acc[c], 0, 0, 0);
  }
  int rowbase = blockIdx.x*64 + 16*wv + 4*quad;
  float div[4];
  #pragma unroll
  for (int r = 0; r < 4; ++r){ int rr = rowbase + r; div[r] = (rr < n) ? dinv[rr] : 0.f; }
  #pragma unroll
  for (int c = 0; c < 6; ++c){
    int col = 16*c + m;
    #pragma unroll
    for (int r = 0; r < 4; ++r){
      int rr = rowbase + r;
      if (rr < n) HS[(size_t)96*rr + col] = f2bf(acc[c][r]*div[r]);
    }
  }
}

// ---------- MFMA mid layer: HS = dinv * (relu(BN(Zb)) @ W), Zb bf16 ----------
__global__ __launch_bounds__(256) void k_linm(const unsigned short* __restrict__ zb,
      const unsigned short* __restrict__ Wtb, const float* __restrict__ st,
      const void* __restrict__ gam, const void* __restrict__ bet,
      const float* __restrict__ flag, const float* __restrict__ dinv,
      unsigned short* __restrict__ HS, int n, float invN){
  __shared__ float sa[96], sc[96];
  __shared__ __align__(16) unsigned short Ys[64][104];
  __shared__ __align__(16) unsigned short Wt[96][104];
  int t = threadIdx.x;
  if (t < 96){
    float isf = flag[0];
    float mu  = st[t]*invN;
    float var = fmaxf(st[96+t]*invN - mu*mu, 0.f);
    float istd = rsqrtf(var + 1e-5f);
    float a = ldf(gam, t, isf)*istd;
    sa[t] = a; sc[t] = ldf(bet, t, isf) - mu*a;
  }
  for (int q = t; q < 1152; q += 256){
    uint4 v = ((const uint4*)Wtb)[q];
    *(uint4*)&Wt[q/12][8*(q - 12*(q/12))] = v;
  }
  __syncthreads();
  // stage Y: 4 threads/row, each 3 uint4s (24 vals) -- clean single-write version
  {
    int row = t >> 2, part = t & 3;
    int node = blockIdx.x*64 + row;
    if (node < n){
      const uint4* zr = (const uint4*)(zb + (size_t)96*node) + 3*part;
      #pragma unroll
      for (int q = 0; q < 3; ++q){
        uint4 zz = zr[q];
        int k = 24*part + 8*q;       // feature index of first element
        float y0 = fmaxf(lo16(zz.x)*sa[k]   + sc[k],   0.f);
        float y1 = fmaxf(hi16(zz.x)*sa[k+1] + sc[k+1], 0.f);
        float y2 = fmaxf(lo16(zz.y)*sa[k+2] + sc[k+2], 0.f);
        float y3 = fmaxf(hi16(zz.y)*sa[k+3] + sc[k+3], 0.f);
        float y4 = fmaxf(lo16(zz.z)*sa[k+4] + sc[k+4], 0.f);
        float y5 = fmaxf(hi16(zz.z)*sa[k+5] + sc[k+5], 0.f);
        float y6 = fmaxf(lo16(zz.w)*sa[k+6] + sc[k+6], 0.f);
        float y7 = fmaxf(hi16(zz.w)*sa[k+7] + sc[k+7], 0.f);
        *(unsigned int*)&Ys[row][k]     = pk2(y0, y1);
        *(unsigned int*)&Ys[row][k + 2] = pk2(y2, y3);
        *(unsigned int*)&Ys[row][k + 4] = pk2(y4, y5);
        *(unsigned int*)&Ys[row][k + 6] = pk2(y6, y7);
      }
    } else {
      unsigned int* yp = (unsigned int*)&Ys[row][24*part];
      #pragma unroll
      for (int q = 0; q < 12; ++q) yp[q] = 0u;
    }
  }
  __syncthreads();

  int wv = t >> 6, lane = t & 63;
  int m = lane & 15, quad = lane >> 4;
  bf16x8 av[3];
  #pragma unroll
  for (int kt = 0; kt < 3; ++kt)
    av[kt] = *(const bf16x8*)&Ys[16*wv + m][32*kt + 8*quad];
  f32x4 acc[6];
  #pragma unroll
  for (int c = 0; c < 6; ++c) acc[c] = (f32x4)(0.f);
  #pragma unroll
  for (int c = 0; c < 6; ++c){
    const unsigned short* wrow = &Wt[16*c + m][8*quad];
    #pragma unroll
    for (int kt = 0; kt < 3; ++kt){
      bf16x8 bv = *(const bf16x8*)(wrow + 32*kt);
      acc[c] = __builtin_amdgcn_mfma_f32_16x16x32_bf16(av[kt], bv, acc[c], 0, 0, 0);
    }
  }
  int rowbase = blockIdx.x*64 + 16*wv + 4*quad;
  float div[4];
  #pragma unroll
  for (int r = 0; r < 4; ++r){ int rr = rowbase + r; div[r] = (rr < n) ? dinv[rr] : 0.f; }
  #pragma unroll
  for (int c = 0; c < 6; ++c){
    int col = 16*c + m;
    #pragma unroll
    for (int r = 0; r < 4; ++r){
      int rr = rowbase + r;
      if (rr < n) HS[(size_t)96*rr + col] = f2bf(acc[c][r]*div[r]);
    }
  }
}

// ---------- layer 4 (96->2, VALU), Zb bf16 ----------
__global__ __launch_bounds__(256) void k_lin4(const unsigned short* __restrict__ zb,
      const float* __restrict__ Wf, const float* __restrict__ st,
      const void* __restrict__ gam, const void* __restrict__ bet,
      const float* __restrict__ flag, const float* __restrict__ dinv,
      float* __restrict__ hs2, int n, float invN){
  __shared__ float sa[96], sc[96];
  int t = threadIdx.x;
  if (t < 96){
    float isf = flag[0];
    float mu  = st[t]*invN;
    float var = fmaxf(st[96+t]*invN - mu*mu, 0.f);
    float istd = rsqrtf(var + 1e-5f);
    float a = ldf(gam, t, isf)*istd;
    sa[t] = a; sc[t] = ldf(bet, t, isf) - mu*a;
  }
  __syncthreads();
  int i = blockIdx.x*blockDim.x + t;
  if (i >= n) return;
  const uint4* zr = (const uint4*)(zb + (size_t)96*i);
  float a0 = 0.f, a1 = 0.f;
  #pragma unroll
  for (int q = 0; q < 12; ++q){
    uint4 zz = zr[q];
    int k = 8*q;
    float y;
    y = fmaxf(lo16(zz.x)*sa[k]   + sc[k],   0.f); a0 += y*Wf[2*k];    a1 += y*Wf[2*k+1];
    y = fmaxf(hi16(zz.x)*sa[k+1] + sc[k+1], 0.f); a0 += y*Wf[2*k+2];  a1 += y*Wf[2*k+3];
    y = fmaxf(lo16(zz.y)*sa[k+2] + sc[k+2], 0.f); a0 += y*Wf[2*k+4];  a1 += y*Wf[2*k+5];
    y = fmaxf(hi16(zz.y)*sa[k+3] + sc[k+3], 0.f); a0 += y*Wf[2*k+6];  a1 += y*Wf[2*k+7];
    y = fmaxf(lo16(zz.z)*sa[k+4] + sc[k+4], 0.f); a0 += y*Wf[2*k+8];  a1 += y*Wf[2*k+9];
    y = fmaxf(hi16(zz.z)*sa[k+5] + sc[k+5], 0.f); a0 += y*Wf[2*k+10]; a1 += y*Wf[2*k+11];
    y = fmaxf(lo16(zz.w)*sa[k+6] + sc[k+6], 0.f); a0 += y*Wf[2*k+12]; a1 += y*Wf[2*k+13];
    y = fmaxf(hi16(zz.w)*sa[k+7] + sc[k+7], 0.f); a0 += y*Wf[2*k+14]; a1 += y*Wf[2*k+15];
  }
  float di = dinv[i];
  hs2[(size_t)2*i]   = di*a0;
  hs2[(size_t)2*i+1] = di*a1;
}

// ---------- CSR gather aggregation (bf16 HS -> bf16 Zb) ----------
#define ACC8(v) { a0+=lo16((v).x); a1+=hi16((v).x); a2+=lo16((v).y); a3+=hi16((v).y); \
                  a4+=lo16((v).z); a5+=hi16((v).z); a6+=lo16((v).w); a7+=hi16((v).w); }
__global__ __launch_bounds__(192) void k_agg(const uint4* __restrict__ hsr,
      const int* __restrict__ rowst, const int* __restrict__ csr,
      const float* __restrict__ dinv, uint4* __restrict__ zb4,
      float* __restrict__ st, int n){
  int t = threadIdx.y*12 + threadIdx.x;
  if (blockIdx.x == 0 && t < 192) st[t] = 0.f;   // zero stats for the following k_stats
  int node = blockIdx.x*16 + threadIdx.y;
  if (node >= n) return;
  int g = threadIdx.x;
  uint4 v = hsr[(size_t)node*12 + g];            // self-loop term
  float a0 = lo16(v.x), a1 = hi16(v.x), a2 = lo16(v.y), a3 = hi16(v.y);
  float a4 = lo16(v.z), a5 = hi16(v.z), a6 = lo16(v.w), a7 = hi16(v.w);
  int b = rowst[node], e = rowst[node+1];
  int j = b;
  for (; j + 3 < e; j += 4){
    int s0 = csr[j], s1 = csr[j+1], s2 = csr[j+2], s3 = csr[j+3];
    uint4 v0 = hsr[(size_t)s0*12 + g];
    uint4 v1 = hsr[(size_t)s1*12 + g];
    uint4 v2 = hsr[(size_t)s2*12 + g];
    uint4 v3 = hsr[(size_t)s3*12 + g];
    ACC8(v0); ACC8(v1); ACC8(v2); ACC8(v3);
  }
  for (; j < e; ++j){
    uint4 vv = hsr[(size_t)csr[j]*12 + g];
    ACC8(vv);
  }
  float di = dinv[node];
  uint4 o;
  o.x = pk2(a0*di, a1*di);
  o.y = pk2(a2*di, a3*di);
  o.z = pk2(a4*di, a5*di);
  o.w = pk2(a6*di, a7*di);
  zb4[(size_t)node*12 + g] = o;
}

__global__ void k_agg2(const float2* __restrict__ hs2, const int* __restrict__ rowst,
                       const int* __restrict__ csr, const float* __restrict__ dinv,
                       const void* __restrict__ b4, const float* __restrict__ flag,
                       void* __restrict__ out, int n){
  int node = blockIdx.x*blockDim.x + threadIdx.x;
  if (node >= n) return;
  float2 a = hs2[node];
  int b = rowst[node], e = rowst[node+1];
  for (int j = b; j < e; ++j){
    float2 v = hs2[csr[j]];
    a.x += v.x; a.y += v.y;
  }
  float isf = flag[0];
  float di = dinv[node];
  float v0 = a.x*di + ldf(b4, 0, isf);
  float v1 = a.y*di + ldf(b4, 1, isf);
  if (isf > 0.5f){
    ((float*)out)[(size_t)2*node]   = v0;
    ((float*)out)[(size_t)2*node+1] = v1;
  } else {
    ((unsigned short*)out)[(size_t)2*node]   = f2bf(v0);
    ((unsigned short*)out)[(size_t)2*node+1] = f2bf(v1);
  }
}

// ---------- batchnorm stats on bf16 Zb ----------
__global__ void k_stats(const unsigned short* __restrict__ zb, float* __restrict__ st, int n){
  int f = threadIdx.x, ty = threadIdx.y;
  float s = 0.f, q = 0.f;
  for (int i = blockIdx.x*4 + ty; i < n; i += gridDim.x*4){
    float y = bfh(zb[(size_t)96*i + f]);
    s += y; q += y*y;
  }
  __shared__ float ls[4][96], lq[4][96];
  ls[ty][f] = s; lq[ty][f] = q;
  __syncthreads();
  if (ty == 0){
    s = ls[0][f]+ls[1][f]+ls[2][f]+ls[3][f];
    q = lq[0][f]+lq[1][f]+lq[2][f]+lq[3][f];
    atomicAdd(&st[f], s); atomicAdd(&st[96+f], q);
  }
}

extern "C" void kernel_launch(void* const* d_in, const int* in_sizes, int n_in,
                              void* d_out, int out_size, void* d_ws, size_t ws_size,
                              hipStream_t stream)
{
  const int B = 256;
  unsigned short* outh = (unsigned short*)d_out;

  if (n_in < 16){
    k_fill<<<(out_size+B-1)/B, B, 0, stream>>>(outh, 0x3F40u, out_size); return;
  }
  const int N = in_sizes[0] / 32;
  const long long E = in_sizes[1] / 2;
  if (in_sizes[0] % 32 != 0 || out_size != 2*N){
    k_fill<<<(out_size+B-1)/B, B, 0, stream>>>(outh, 0x3F60u, out_size); return;
  }

  // ---- workspace layout ----
  size_t Npad = ((size_t)N + 3) & ~(size_t)3;
  float* ws   = (float*)d_ws;
  float* dinv = ws;                               // Npad
  float* hs2  = dinv + Npad;                      // 2N
  float* st   = hs2 + (size_t)2*N;                // 384
  float* flag = st + 384;                         // 4
  float* W4f  = flag + 4;                         // 192
  unsigned short* Wt1b = (unsigned short*)(W4f + 192);   // 3072 bf16
  unsigned short* Wt2b = Wt1b + 3072;             // 9216
  unsigned short* Wt3b = Wt2b + 9216;             // 9216
  int* cnt    = (int*)(Wt3b + 9216);              // N
  int* cursor = cnt + N;                          // N
  int* rowst  = cursor + N;                       // N+1
  int* bsum   = rowst + N + 1;                    // 256
  int* boff   = bsum + 256;                       // 256
  int* csr    = boff + 256;                       // E
  uintptr_t hp_ = (uintptr_t)(csr + E);
  hp_ = (hp_ + 15) & ~(uintptr_t)15;
  unsigned short* HS = (unsigned short*)hp_;      // 96N bf16
  unsigned short* Zb = HS + (size_t)96*N;         // 96N bf16

  size_t needB = ((uintptr_t)(Zb + (size_t)96*N) - (uintptr_t)d_ws) + 64;
  if (ws_size < needB){
    k_fill<<<(out_size+B-1)/B, B, 0, stream>>>(outh, 0x3F00u, out_size); return;
  }

  const void* x  = d_in[0];
  const int*  ei = (const int*)d_in[1];
  const void* W1 = d_in[2];
  const void* g1 = d_in[4];  const void* be1 = d_in[5];
  const void* W2 = d_in[6];
  const void* g2 = d_in[8];  const void* be2 = d_in[9];
  const void* W3 = d_in[10];
  const void* g3 = d_in[12]; const void* be3 = d_in[13];
  const void* W4 = d_in[14];
  const void* b4 = d_in[15];

  int gN  = (N + B - 1)/B;
  int gE  = (int)((E + B - 1)/B);
  int nb  = (N + 255)/256;            // <= 256 assumed
  int gA  = (N + 15)/16;
  int gL  = (N + 63)/64;
  float invN = 1.0f / (float)N;
  dim3 ablk(12,16);
  dim3 sblk(96,4);

  // dtype detection + weight convert + CSR build
  k_detect<<<1, 256, 0, stream>>>((const unsigned short*)x, (const unsigned int*)ei,
                                  flag, in_sizes[0], E);
  hipMemsetAsync(cnt, 0, (size_t)N*sizeof(int), stream);
  k_cvtW<<<(9216+B-1)/B, B, 0, stream>>>(W1, W2, W3, W4, flag, Wt1b, Wt2b, Wt3b, W4f);
  k_cnt<<<gE, B, 0, stream>>>(ei, flag, cnt, E, N);
  k_bsum<<<nb, 256, 0, stream>>>(cnt, bsum, N);
  k_sscan<<<1, 256, 0, stream>>>(bsum, boff, rowst + N, nb);
  k_emit<<<nb, 256, 0, stream>>>(cnt, boff, rowst, cursor, dinv, N);
  k_fill_slots<<<gE, B, 0, stream>>>(ei, flag, cursor, csr, E, N);

  // layer 1 (MFMA)
  k_lin1m<<<gL, B, 0, stream>>>(x, Wt1b, flag, dinv, HS, N);
  k_agg<<<gA, ablk, 0, stream>>>((const uint4*)HS, rowst, csr, dinv, (uint4*)Zb, st, N);
  k_stats<<<512, sblk, 0, stream>>>(Zb, st, N);

  // layer 2 (MFMA)
  k_linm<<<gL, B, 0, stream>>>(Zb, Wt2b, st, g1, be1, flag, dinv, HS, N, invN);
  k_agg<<<gA, ablk, 0, stream>>>((const uint4*)HS, rowst, csr, dinv, (uint4*)Zb, st, N);
  k_stats<<<512, sblk, 0, stream>>>(Zb, st, N);

  // layer 3 (MFMA)
  k_linm<<<gL, B, 0, stream>>>(Zb, Wt3b, st, g2, be2, flag, dinv, HS, N, invN);
  k_agg<<<gA, ablk, 0, stream>>>((const uint4*)HS, rowst, csr, dinv, (uint4*)Zb, st, N);
  k_stats<<<512, sblk, 0, stream>>>(Zb, st, N);

  // layer 4
  k_lin4<<<gN, B, 0, stream>>>(Zb, W4f, st, g3, be3, flag, dinv, hs2, N, invN);
  k_agg2<<<gN, B, 0, stream>>>((const float2*)hs2, rowst, csr, dinv, b4, flag, d_out, N);
}

// Round 10
// 373.244 us; speedup vs baseline: 1.0223x; 1.0223x over previous
//
#include <hip/hip_runtime.h>
#include <hip/hip_bf16.h>

using bf16x8 = __attribute__((ext_vector_type(8))) short;
using f32x4  = __attribute__((ext_vector_type(4))) float;

// ---------- dtype-dispatched load helpers ----------
__device__ __forceinline__ float ldf(const void* p, size_t i, float isf){
  if (isf > 0.5f) return ((const float*)p)[i];
  unsigned int u = ((unsigned int)((const unsigned short*)p)[i]) << 16;
  return __uint_as_float(u);
}
__device__ __forceinline__ unsigned short f2bf(float v){
  unsigned int u = __float_as_uint(v);
  u = (u + 0x7FFFu + ((u >> 16) & 1u)) >> 16;   // RNE
  return (unsigned short)u;
}
__device__ __forceinline__ unsigned int pk2(float a, float b){
  return (unsigned int)f2bf(a) | ((unsigned int)f2bf(b) << 16);
}
__device__ __forceinline__ float lo16(unsigned int u){ return __uint_as_float(u << 16); }
__device__ __forceinline__ float hi16(unsigned int u){ return __uint_as_float(u & 0xFFFF0000u); }
__device__ __forceinline__ float bfh(unsigned short h){ return __uint_as_float(((unsigned int)h) << 16); }

// ---------- diagnostics ----------
__global__ void k_fill(unsigned short* o, unsigned short v, int n){
  int i = blockIdx.x*blockDim.x + threadIdx.x;
  if (i < n) o[i] = v;
}

// ---------- dtype detector ----------
__global__ void k_detect(const unsigned short* xh, const unsigned int* eu,
                         float* flag, int nelemX, long long E){
  __shared__ int sf32, si64;
  if (threadIdx.x == 0){ sf32 = 0; si64 = 1; }
  __syncthreads();
  int t = threadIdx.x;
  int i = 2*t;
  if (i < nelemX){
    unsigned e8 = (xh[i] >> 7) & 0xFFu;
    if (e8 >= 140u) sf32 = 1;
  }
  if ((long long)(2*t + 1) < 2*E){
    if (eu[2*t + 1] != 0u) si64 = 0;
  }
  __syncthreads();
  if (t == 0){ flag[0] = (float)sf32; flag[1] = (float)si64; }
}

// ---------- weight pre-convert: transposed bf16 for MFMA B-operand, fp32 for W4 ----------
__global__ void k_cvtW(const void* W1, const void* W2, const void* W3, const void* W4,
                       const float* __restrict__ flag,
                       unsigned short* __restrict__ Wt1, unsigned short* __restrict__ Wt2,
                       unsigned short* __restrict__ Wt3, float* __restrict__ W4f){
  float isf = flag[0];
  int t = blockIdx.x*blockDim.x + threadIdx.x;
  if (t < 3072){ int nn = t >> 5, k = t & 31; Wt1[t] = f2bf(ldf(W1, (size_t)96*k + nn, isf)); }
  if (t < 9216){
    int nn = t/96, k = t - 96*nn;
    Wt2[t] = f2bf(ldf(W2, (size_t)96*k + nn, isf));
    Wt3[t] = f2bf(ldf(W3, (size_t)96*k + nn, isf));
  }
  if (t < 192) W4f[t] = ldf(W4, t, isf);
}

// ---------- CSR build ----------
__global__ void k_cnt(const int* __restrict__ ei, const float* __restrict__ flag,
                      int* __restrict__ cnt, long long E, int n){
  long long i = (long long)blockIdx.x*blockDim.x + threadIdx.x;
  if (i >= E) return;
  int d = (flag[1] > 0.5f) ? ei[2*E + 2*i] : ei[E + i];
  if ((unsigned)d < (unsigned)n) atomicAdd(&cnt[d], 1);
}

__global__ void k_bsum(const int* __restrict__ cnt, int* __restrict__ bsum, int n){
  int i = blockIdx.x*256 + threadIdx.x;
  int v = (i < n) ? cnt[i] : 0;
  #pragma unroll
  for (int off = 32; off; off >>= 1) v += __shfl_down(v, off, 64);
  __shared__ int w[4];
  if ((threadIdx.x & 63) == 0) w[threadIdx.x >> 6] = v;
  __syncthreads();
  if (threadIdx.x == 0) bsum[blockIdx.x] = w[0]+w[1]+w[2]+w[3];
}

__global__ void k_sscan(const int* __restrict__ bsum, int* __restrict__ boff,
                        int* __restrict__ rowstN, int nb){
  int t = threadIdx.x;
  int v = (t < nb) ? bsum[t] : 0;
  int lane = t & 63, wid = t >> 6;
  int s = v;
  #pragma unroll
  for (int off = 1; off < 64; off <<= 1){
    int u = __shfl_up(s, off, 64);
    if (lane >= off) s += u;
  }
  __shared__ int wt[4];
  if (lane == 63) wt[wid] = s;
  __syncthreads();
  int add = 0;
  for (int w = 0; w < wid; ++w) add += wt[w];
  int incl = s + add;
  if (t < nb) boff[t] = incl - v;
  if (t == nb - 1) *rowstN = incl;
}

// also initializes cursor[i] = rowst[i] so fill_slots needs no rowst read
__global__ void k_emit(const int* __restrict__ cnt, const int* __restrict__ boff,
                       int* __restrict__ rowst, int* __restrict__ cursor,
                       float* __restrict__ dinv, int n){
  int i = blockIdx.x*256 + threadIdx.x;
  int v = (i < n) ? cnt[i] : 0;
  int lane = threadIdx.x & 63, wid = threadIdx.x >> 6;
  int s = v;
  #pragma unroll
  for (int off = 1; off < 64; off <<= 1){
    int u = __shfl_up(s, off, 64);
    if (lane >= off) s += u;
  }
  __shared__ int wt[4];
  if (lane == 63) wt[wid] = s;
  __syncthreads();
  int add = 0;
  for (int w = 0; w < wid; ++w) add += wt[w];
  if (i < n){
    int r = boff[blockIdx.x] + add + s - v;
    rowst[i] = r;
    cursor[i] = r;
    dinv[i]  = rsqrtf((float)(1 + v));
  }
}

// cursor pre-initialized to rowst; IT = csr entry type (u16 when N < 65536)
template<typename IT>
__global__ void k_fill_slots(const int* __restrict__ ei, const float* __restrict__ flag,
                             int* __restrict__ cursor, IT* __restrict__ csr,
                             long long E, int n){
  long long i = (long long)blockIdx.x*blockDim.x + threadIdx.x;
  if (i >= E) return;
  int s, d;
  if (flag[1] > 0.5f){ s = ei[2*i]; d = ei[2*E + 2*i]; }
  else               { s = ei[i];   d = ei[E + i];     }
  if ((unsigned)s < (unsigned)n && (unsigned)d < (unsigned)n){
    int p = atomicAdd(&cursor[d], 1);
    csr[p] = (IT)s;
  }
}

// ---------- MFMA layer 1: HS = dinv * (x @ W1), x N*32 ----------
__global__ __launch_bounds__(256) void k_lin1m(const void* __restrict__ x,
      const unsigned short* __restrict__ Wt1b, const float* __restrict__ flag,
      const float* __restrict__ dinv, unsigned short* __restrict__ HS, int n){
  __shared__ __align__(16) unsigned short Xs[64][40];
  __shared__ __align__(16) unsigned short Wt[96][40];
  int t = threadIdx.x;
  float isf = flag[0];
  for (int q = t; q < 384; q += 256){
    uint4 v = ((const uint4*)Wt1b)[q];
    *(uint4*)&Wt[q >> 2][(q & 3)*8] = v;
  }
  {
    int row = t >> 2, part = t & 3;
    int node = blockIdx.x*64 + row;
    uint4 o;
    if (node < n){
      if (isf > 0.5f){
        const float* xr = (const float*)x + (size_t)32*node + 8*part;
        o.x = pk2(xr[0], xr[1]); o.y = pk2(xr[2], xr[3]);
        o.z = pk2(xr[4], xr[5]); o.w = pk2(xr[6], xr[7]);
      } else {
        o = ((const uint4*)x)[(size_t)4*node + part];
      }
    } else { o.x = o.y = o.z = o.w = 0u; }
    *(uint4*)&Xs[row][8*part] = o;
  }
  __syncthreads();

  int wv = t >> 6, lane = t & 63;
  int m = lane & 15, quad = lane >> 4;
  bf16x8 av = *(const bf16x8*)&Xs[16*wv + m][8*quad];
  f32x4 acc[6];
  #pragma unroll
  for (int c = 0; c < 6; ++c) acc[c] = (f32x4)(0.f);
  #pragma unroll
  for (int c = 0; c < 6; ++c){
    bf16x8 bv = *(const bf16x8*)&Wt[16*c + m][8*quad];
    acc[c] = __builtin_amdgcn_mfma_f32_16x16x32_bf16(av, bv, acc[c], 0, 0, 0);
  }
  int rowbase = blockIdx.x*64 + 16*wv + 4*quad;
  float div[4];
  #pragma unroll
  for (int r = 0; r < 4; ++r){ int rr = rowbase + r; div[r] = (rr < n) ? dinv[rr] : 0.f; }
  #pragma unroll
  for (int c = 0; c < 6; ++c){
    int col = 16*c + m;
    #pragma unroll
    for (int r = 0; r < 4; ++r){
      int rr = rowbase + r;
      if (rr < n) HS[(size_t)96*rr + col] = f2bf(acc[c][r]*div[r]);
    }
  }
}

// ---------- MFMA mid layer: HS = dinv * (relu(BN(Zb)) @ W), Zb bf16 ----------
__global__ __launch_bounds__(256) void k_linm(const unsigned short* __restrict__ zb,
      const unsigned short* __restrict__ Wtb, const float* __restrict__ st,
      const void* __restrict__ gam, const void* __restrict__ bet,
      const float* __restrict__ flag, const float* __restrict__ dinv,
      unsigned short* __restrict__ HS, int n, float invN){
  __shared__ float sa[96], sc[96];
  __shared__ __align__(16) unsigned short Ys[64][104];
  __shared__ __align__(16) unsigned short Wt[96][104];
  int t = threadIdx.x;
  if (t < 96){
    float isf = flag[0];
    float mu  = st[t]*invN;
    float var = fmaxf(st[96+t]*invN - mu*mu, 0.f);
    float istd = rsqrtf(var + 1e-5f);
    float a = ldf(gam, t, isf)*istd;
    sa[t] = a; sc[t] = ldf(bet, t, isf) - mu*a;
  }
  for (int q = t; q < 1152; q += 256){
    uint4 v = ((const uint4*)Wtb)[q];
    *(uint4*)&Wt[q/12][8*(q - 12*(q/12))] = v;
  }
  __syncthreads();
  // stage Y: 4 threads/row, each 3 uint4s (24 vals)
  {
    int row = t >> 2, part = t & 3;
    int node = blockIdx.x*64 + row;
    if (node < n){
      const uint4* zr = (const uint4*)(zb + (size_t)96*node) + 3*part;
      #pragma unroll
      for (int q = 0; q < 3; ++q){
        uint4 zz = zr[q];
        int k = 24*part + 8*q;
        float y0 = fmaxf(lo16(zz.x)*sa[k]   + sc[k],   0.f);
        float y1 = fmaxf(hi16(zz.x)*sa[k+1] + sc[k+1], 0.f);
        float y2 = fmaxf(lo16(zz.y)*sa[k+2] + sc[k+2], 0.f);
        float y3 = fmaxf(hi16(zz.y)*sa[k+3] + sc[k+3], 0.f);
        float y4 = fmaxf(lo16(zz.z)*sa[k+4] + sc[k+4], 0.f);
        float y5 = fmaxf(hi16(zz.z)*sa[k+5] + sc[k+5], 0.f);
        float y6 = fmaxf(lo16(zz.w)*sa[k+6] + sc[k+6], 0.f);
        float y7 = fmaxf(hi16(zz.w)*sa[k+7] + sc[k+7], 0.f);
        *(unsigned int*)&Ys[row][k]     = pk2(y0, y1);
        *(unsigned int*)&Ys[row][k + 2] = pk2(y2, y3);
        *(unsigned int*)&Ys[row][k + 4] = pk2(y4, y5);
        *(unsigned int*)&Ys[row][k + 6] = pk2(y6, y7);
      }
    } else {
      unsigned int* yp = (unsigned int*)&Ys[row][24*part];
      #pragma unroll
      for (int q = 0; q < 12; ++q) yp[q] = 0u;
    }
  }
  __syncthreads();

  int wv = t >> 6, lane = t & 63;
  int m = lane & 15, quad = lane >> 4;
  bf16x8 av[3];
  #pragma unroll
  for (int kt = 0; kt < 3; ++kt)
    av[kt] = *(const bf16x8*)&Ys[16*wv + m][32*kt + 8*quad];
  f32x4 acc[6];
  #pragma unroll
  for (int c = 0; c < 6; ++c) acc[c] = (f32x4)(0.f);
  #pragma unroll
  for (int c = 0; c < 6; ++c){
    const unsigned short* wrow = &Wt[16*c + m][8*quad];
    #pragma unroll
    for (int kt = 0; kt < 3; ++kt){
      bf16x8 bv = *(const bf16x8*)(wrow + 32*kt);
      acc[c] = __builtin_amdgcn_mfma_f32_16x16x32_bf16(av[kt], bv, acc[c], 0, 0, 0);
    }
  }
  int rowbase = blockIdx.x*64 + 16*wv + 4*quad;
  float div[4];
  #pragma unroll
  for (int r = 0; r < 4; ++r){ int rr = rowbase + r; div[r] = (rr < n) ? dinv[rr] : 0.f; }
  #pragma unroll
  for (int c = 0; c < 6; ++c){
    int col = 16*c + m;
    #pragma unroll
    for (int r = 0; r < 4; ++r){
      int rr = rowbase + r;
      if (rr < n) HS[(size_t)96*rr + col] = f2bf(acc[c][r]*div[r]);
    }
  }
}

// ---------- layer 4 (96->2, VALU), Zb bf16 ----------
__global__ __launch_bounds__(256) void k_lin4(const unsigned short* __restrict__ zb,
      const float* __restrict__ Wf, const float* __restrict__ st,
      const void* __restrict__ gam, const void* __restrict__ bet,
      const float* __restrict__ flag, const float* __restrict__ dinv,
      float* __restrict__ hs2, int n, float invN){
  __shared__ float sa[96], sc[96];
  int t = threadIdx.x;
  if (t < 96){
    float isf = flag[0];
    float mu  = st[t]*invN;
    float var = fmaxf(st[96+t]*invN - mu*mu, 0.f);
    float istd = rsqrtf(var + 1e-5f);
    float a = ldf(gam, t, isf)*istd;
    sa[t] = a; sc[t] = ldf(bet, t, isf) - mu*a;
  }
  __syncthreads();
  int i = blockIdx.x*blockDim.x + t;
  if (i >= n) return;
  const uint4* zr = (const uint4*)(zb + (size_t)96*i);
  float a0 = 0.f, a1 = 0.f;
  #pragma unroll
  for (int q = 0; q < 12; ++q){
    uint4 zz = zr[q];
    int k = 8*q;
    float y;
    y = fmaxf(lo16(zz.x)*sa[k]   + sc[k],   0.f); a0 += y*Wf[2*k];    a1 += y*Wf[2*k+1];
    y = fmaxf(hi16(zz.x)*sa[k+1] + sc[k+1], 0.f); a0 += y*Wf[2*k+2];  a1 += y*Wf[2*k+3];
    y = fmaxf(lo16(zz.y)*sa[k+2] + sc[k+2], 0.f); a0 += y*Wf[2*k+4];  a1 += y*Wf[2*k+5];
    y = fmaxf(hi16(zz.y)*sa[k+3] + sc[k+3], 0.f); a0 += y*Wf[2*k+6];  a1 += y*Wf[2*k+7];
    y = fmaxf(lo16(zz.z)*sa[k+4] + sc[k+4], 0.f); a0 += y*Wf[2*k+8];  a1 += y*Wf[2*k+9];
    y = fmaxf(hi16(zz.z)*sa[k+5] + sc[k+5], 0.f); a0 += y*Wf[2*k+10]; a1 += y*Wf[2*k+11];
    y = fmaxf(lo16(zz.w)*sa[k+6] + sc[k+6], 0.f); a0 += y*Wf[2*k+12]; a1 += y*Wf[2*k+13];
    y = fmaxf(hi16(zz.w)*sa[k+7] + sc[k+7], 0.f); a0 += y*Wf[2*k+14]; a1 += y*Wf[2*k+15];
  }
  float di = dinv[i];
  hs2[(size_t)2*i]   = di*a0;
  hs2[(size_t)2*i+1] = di*a1;
}

// ---------- CSR gather aggregation (bf16 HS -> bf16 Zb), unroll 8 ----------
#define ACC8(v) { a0+=lo16((v).x); a1+=hi16((v).x); a2+=lo16((v).y); a3+=hi16((v).y); \
                  a4+=lo16((v).z); a5+=hi16((v).z); a6+=lo16((v).w); a7+=hi16((v).w); }
template<typename IT>
__global__ __launch_bounds__(192) void k_agg(const uint4* __restrict__ hsr,
      const int* __restrict__ rowst, const IT* __restrict__ csr,
      const float* __restrict__ dinv, uint4* __restrict__ zb4,
      float* __restrict__ st, int n){
  int t = threadIdx.y*12 + threadIdx.x;
  if (blockIdx.x == 0 && t < 192) st[t] = 0.f;   // zero stats for the following k_stats
  int node = blockIdx.x*16 + threadIdx.y;
  if (node >= n) return;
  int g = threadIdx.x;
  uint4 v = hsr[(size_t)node*12 + g];            // self-loop term
  float a0 = lo16(v.x), a1 = hi16(v.x), a2 = lo16(v.y), a3 = hi16(v.y);
  float a4 = lo16(v.z), a5 = hi16(v.z), a6 = lo16(v.w), a7 = hi16(v.w);
  int b = rowst[node], e = rowst[node+1];
  int j = b;
  for (; j + 7 < e; j += 8){
    uint4 v0 = hsr[(size_t)csr[j]  *12 + g];
    uint4 v1 = hsr[(size_t)csr[j+1]*12 + g];
    uint4 v2 = hsr[(size_t)csr[j+2]*12 + g];
    uint4 v3 = hsr[(size_t)csr[j+3]*12 + g];
    uint4 v4 = hsr[(size_t)csr[j+4]*12 + g];
    uint4 v5 = hsr[(size_t)csr[j+5]*12 + g];
    uint4 v6 = hsr[(size_t)csr[j+6]*12 + g];
    uint4 v7 = hsr[(size_t)csr[j+7]*12 + g];
    ACC8(v0); ACC8(v1); ACC8(v2); ACC8(v3);
    ACC8(v4); ACC8(v5); ACC8(v6); ACC8(v7);
  }
  for (; j + 3 < e; j += 4){
    uint4 v0 = hsr[(size_t)csr[j]  *12 + g];
    uint4 v1 = hsr[(size_t)csr[j+1]*12 + g];
    uint4 v2 = hsr[(size_t)csr[j+2]*12 + g];
    uint4 v3 = hsr[(size_t)csr[j+3]*12 + g];
    ACC8(v0); ACC8(v1); ACC8(v2); ACC8(v3);
  }
  for (; j < e; ++j){
    uint4 vv = hsr[(size_t)csr[j]*12 + g];
    ACC8(vv);
  }
  float di = dinv[node];
  uint4 o;
  o.x = pk2(a0*di, a1*di);
  o.y = pk2(a2*di, a3*di);
  o.z = pk2(a4*di, a5*di);
  o.w = pk2(a6*di, a7*di);
  zb4[(size_t)node*12 + g] = o;
}

template<typename IT>
__global__ void k_agg2(const float2* __restrict__ hs2, const int* __restrict__ rowst,
                       const IT* __restrict__ csr, const float* __restrict__ dinv,
                       const void* __restrict__ b4, const float* __restrict__ flag,
                       void* __restrict__ out, int n){
  int node = blockIdx.x*blockDim.x + threadIdx.x;
  if (node >= n) return;
  float2 a = hs2[node];
  int b = rowst[node], e = rowst[node+1];
  for (int j = b; j < e; ++j){
    float2 v = hs2[(size_t)csr[j]];
    a.x += v.x; a.y += v.y;
  }
  float isf = flag[0];
  float di = dinv[node];
  float v0 = a.x*di + ldf(b4, 0, isf);
  float v1 = a.y*di + ldf(b4, 1, isf);
  if (isf > 0.5f){
    ((float*)out)[(size_t)2*node]   = v0;
    ((float*)out)[(size_t)2*node+1] = v1;
  } else {
    ((unsigned short*)out)[(size_t)2*node]   = f2bf(v0);
    ((unsigned short*)out)[(size_t)2*node+1] = f2bf(v1);
  }
}

// ---------- batchnorm stats on bf16 Zb ----------
__global__ void k_stats(const unsigned short* __restrict__ zb, float* __restrict__ st, int n){
  int f = threadIdx.x, ty = threadIdx.y;
  float s = 0.f, q = 0.f;
  for (int i = blockIdx.x*4 + ty; i < n; i += gridDim.x*4){
    float y = bfh(zb[(size_t)96*i + f]);
    s += y; q += y*y;
  }
  __shared__ float ls[4][96], lq[4][96];
  ls[ty][f] = s; lq[ty][f] = q;
  __syncthreads();
  if (ty == 0){
    s = ls[0][f]+ls[1][f]+ls[2][f]+ls[3][f];
    q = lq[0][f]+lq[1][f]+lq[2][f]+lq[3][f];
    atomicAdd(&st[f], s); atomicAdd(&st[96+f], q);
  }
}

extern "C" void kernel_launch(void* const* d_in, const int* in_sizes, int n_in,
                              void* d_out, int out_size, void* d_ws, size_t ws_size,
                              hipStream_t stream)
{
  const int B = 256;
  unsigned short* outh = (unsigned short*)d_out;

  if (n_in < 16){
    k_fill<<<(out_size+B-1)/B, B, 0, stream>>>(outh, 0x3F40u, out_size); return;
  }
  const int N = in_sizes[0] / 32;
  const long long E = in_sizes[1] / 2;
  if (in_sizes[0] % 32 != 0 || out_size != 2*N){
    k_fill<<<(out_size+B-1)/B, B, 0, stream>>>(outh, 0x3F60u, out_size); return;
  }
  const bool u16 = (N < 65536);

  // ---- workspace layout ----
  size_t Npad = ((size_t)N + 3) & ~(size_t)3;
  float* ws   = (float*)d_ws;
  float* dinv = ws;                               // Npad
  float* hs2  = dinv + Npad;                      // 2N
  float* st   = hs2 + (size_t)2*N;                // 384
  float* flag = st + 384;                         // 4
  float* W4f  = flag + 4;                         // 192
  unsigned short* Wt1b = (unsigned short*)(W4f + 192);   // 3072 bf16
  unsigned short* Wt2b = Wt1b + 3072;             // 9216
  unsigned short* Wt3b = Wt2b + 9216;             // 9216
  int* cnt    = (int*)(Wt3b + 9216);              // N
  int* cursor = cnt + N;                          // N
  int* rowst  = cursor + N;                       // N+1
  int* bsum   = rowst + N + 1;                    // 256
  int* boff   = bsum + 256;                       // 256
  void* csrv  = (void*)(boff + 256);              // E entries (u16 or int)
  size_t csrBytes = (size_t)E * (u16 ? 2 : 4);
  uintptr_t hp_ = (uintptr_t)csrv + csrBytes;
  hp_ = (hp_ + 15) & ~(uintptr_t)15;
  unsigned short* HS = (unsigned short*)hp_;      // 96N bf16
  unsigned short* Zb = HS + (size_t)96*N;         // 96N bf16

  size_t needB = ((uintptr_t)(Zb + (size_t)96*N) - (uintptr_t)d_ws) + 64;
  if (ws_size < needB){
    k_fill<<<(out_size+B-1)/B, B, 0, stream>>>(outh, 0x3F00u, out_size); return;
  }

  const void* x  = d_in[0];
  const int*  ei = (const int*)d_in[1];
  const void* W1 = d_in[2];
  const void* g1 = d_in[4];  const void* be1 = d_in[5];
  const void* W2 = d_in[6];
  const void* g2 = d_in[8];  const void* be2 = d_in[9];
  const void* W3 = d_in[10];
  const void* g3 = d_in[12]; const void* be3 = d_in[13];
  const void* W4 = d_in[14];
  const void* b4 = d_in[15];

  int gN  = (N + B - 1)/B;
  int gE  = (int)((E + B - 1)/B);
  int nb  = (N + 255)/256;            // <= 256 assumed
  int gA  = (N + 15)/16;
  int gL  = (N + 63)/64;
  float invN = 1.0f / (float)N;
  dim3 ablk(12,16);
  dim3 sblk(96,4);

  // dtype detection + weight convert + CSR build
  k_detect<<<1, 256, 0, stream>>>((const unsigned short*)x, (const unsigned int*)ei,
                                  flag, in_sizes[0], E);
  hipMemsetAsync(cnt, 0, (size_t)N*sizeof(int), stream);
  k_cvtW<<<(9216+B-1)/B, B, 0, stream>>>(W1, W2, W3, W4, flag, Wt1b, Wt2b, Wt3b, W4f);
  k_cnt<<<gE, B, 0, stream>>>(ei, flag, cnt, E, N);
  k_bsum<<<nb, 256, 0, stream>>>(cnt, bsum, N);
  k_sscan<<<1, 256, 0, stream>>>(bsum, boff, rowst + N, nb);
  k_emit<<<nb, 256, 0, stream>>>(cnt, boff, rowst, cursor, dinv, N);

  if (u16){
    unsigned short* csr = (unsigned short*)csrv;
    k_fill_slots<unsigned short><<<gE, B, 0, stream>>>(ei, flag, cursor, csr, E, N);

    k_lin1m<<<gL, B, 0, stream>>>(x, Wt1b, flag, dinv, HS, N);
    k_agg<unsigned short><<<gA, ablk, 0, stream>>>((const uint4*)HS, rowst, csr, dinv, (uint4*)Zb, st, N);
    k_stats<<<512, sblk, 0, stream>>>(Zb, st, N);

    k_linm<<<gL, B, 0, stream>>>(Zb, Wt2b, st, g1, be1, flag, dinv, HS, N, invN);
    k_agg<unsigned short><<<gA, ablk, 0, stream>>>((const uint4*)HS, rowst, csr, dinv, (uint4*)Zb, st, N);
    k_stats<<<512, sblk, 0, stream>>>(Zb, st, N);

    k_linm<<<gL, B, 0, stream>>>(Zb, Wt3b, st, g2, be2, flag, dinv, HS, N, invN);
    k_agg<unsigned short><<<gA, ablk, 0, stream>>>((const uint4*)HS, rowst, csr, dinv, (uint4*)Zb, st, N);
    k_stats<<<512, sblk, 0, stream>>>(Zb, st, N);

    k_lin4<<<gN, B, 0, stream>>>(Zb, W4f, st, g3, be3, flag, dinv, hs2, N, invN);
    k_agg2<unsigned short><<<gN, B, 0, stream>>>((const float2*)hs2, rowst, csr, dinv, b4, flag, d_out, N);
  } else {
    int* csr = (int*)csrv;
    k_fill_slots<int><<<gE, B, 0, stream>>>(ei, flag, cursor, csr, E, N);

    k_lin1m<<<gL, B, 0, stream>>>(x, Wt1b, flag, dinv, HS, N);
    k_agg<int><<<gA, ablk, 0, stream>>>((const uint4*)HS, rowst, csr, dinv, (uint4*)Zb, st, N);
    k_stats<<<512, sblk, 0, stream>>>(Zb, st, N);

    k_linm<<<gL, B, 0, stream>>>(Zb, Wt2b, st, g1, be1, flag, dinv, HS, N, invN);
    k_agg<int><<<gA, ablk, 0, stream>>>((const uint4*)HS, rowst, csr, dinv, (uint4*)Zb, st, N);
    k_stats<<<512, sblk, 0, stream>>>(Zb, st, N);

    k_linm<<<gL, B, 0, stream>>>(Zb, Wt3b, st, g2, be2, flag, dinv, HS, N, invN);
    k_agg<int><<<gA, ablk, 0, stream>>>((const uint4*)HS, rowst, csr, dinv, (uint4*)Zb, st, N);
    k_stats<<<512, sblk, 0, stream>>>(Zb, st, N);

    k_lin4<<<gN, B, 0, stream>>>(Zb, W4f, st, g3, be3, flag, dinv, hs2, N, invN);
    k_agg2<int><<<gN, B, 0, stream>>>((const float2*)hs2, rowst, csr, dinv, b4, flag, d_out, N);
  }
}